// Round 1
// baseline (202.133 us; speedup 1.0000x reference)
//
#include <hip/hip_runtime.h>

// CRF NLL: B=1024, T=2048, K=9 (START=7, STOP=8, NEG=-10000).
// Strategy:
//  - Reduce to 7 active states (exp(NEG)=0 kills row START / col STOP).
//  - Linear-space forward with per-step max renormalization (log-scale s).
//  - Chunk time into C=32 chunks of L=64; each chunk computes its 7x7
//    transfer matrix; columns are independent -> 1 lane per column.
//    Lane 7 of each 8-lane group computes the gold-score partial.
//  - Combine kernel folds 32 log-matrices per sentence (7 lanes/sentence),
//    adds STOP readout, subtracts gold; reduce kernel takes the mean.

#define START_TAG 7
#define STOP_TAG  8
#define KDIM      9
#define NS        7
#define CHUNKS    32
#define NEGINF    (-1e30f)

__global__ __launch_bounds__(256) void crf_chunk_kernel(
    const float* __restrict__ feats,
    const float* __restrict__ trans,   // 9x9
    const int*   __restrict__ tags,
    const int*   __restrict__ lengths,
    float* __restrict__ logM,          // [B][CHUNKS][7*7] row-major rows j
    float* __restrict__ goldp,         // [B][CHUNKS]
    int B, int T, int L)
{
    __shared__ float s_trans[81];
    __shared__ float s_E[49];
    if (threadIdx.x < 81) s_trans[threadIdx.x] = trans[threadIdx.x];
    __syncthreads();
    if (threadIdx.x < 49) {
        int j = threadIdx.x / 7, i = threadIdx.x % 7;
        s_E[threadIdx.x] = __expf(s_trans[j * 9 + i]);
    }
    __syncthreads();

    int gtid  = blockIdx.x * blockDim.x + threadIdx.x;
    int lane8 = gtid & 7;
    int bc    = gtid >> 3;
    int c     = bc & (CHUNKS - 1);
    int b     = bc >> 5;               // log2(CHUNKS) = 5
    if (b >= B) return;

    int len  = lengths[b];
    int t0   = c * L;
    int tend = min(t0 + L, len);

    if (lane8 == 7) {
        // ---- gold-score lane: covers t in [t0, tend) ----
        if (t0 >= len) return;
        const int*   tg = tags  + (long)b * T;
        const float* fb = feats + (long)b * T * KDIM;
        float g = 0.f;
        int prev = (t0 == 0) ? START_TAG : tg[t0 - 1];
        for (int t = t0; t < tend; ++t) {
            int cur = tg[t];
            g += s_trans[cur * 9 + prev] + fb[t * KDIM + cur];
            prev = cur;
        }
        if (len - 1 < t0 + L) g += s_trans[STOP_TAG * 9 + tg[len - 1]];
        goldp[b * CHUNKS + c] = g;
        return;
    }

    // ---- matrix lane: column `col` of chunk matrix over t in [max(t0,1), tend) ----
    int col    = lane8;
    int tstart = max(t0, 1);           // t=0 handled analytically in combine
    if (tstart >= len) return;

    float E[NS][NS];
    #pragma unroll
    for (int j = 0; j < NS; ++j)
        #pragma unroll
        for (int i = 0; i < NS; ++i)
            E[j][i] = s_E[j * 7 + i];

    float p[NS];
    #pragma unroll
    for (int j = 0; j < NS; ++j) p[j] = (j == col) ? 1.f : 0.f;
    float s = 0.f;

    const float* fb = feats + ((long)b * T + tstart) * KDIM;
    for (int t = tstart; t < tend; ++t) {
        float f0 = fb[0], f1 = fb[1], f2 = fb[2], f3 = fb[3];
        float f4 = fb[4], f5 = fb[5], f6 = fb[6];
        fb += KDIM;
        float f[NS] = {f0, f1, f2, f3, f4, f5, f6};
        float q[NS];
        #pragma unroll
        for (int j = 0; j < NS; ++j) {
            float acc = E[j][0] * p[0];
            #pragma unroll
            for (int i = 1; i < NS; ++i) acc = fmaf(E[j][i], p[i], acc);
            q[j] = acc * __expf(f[j]);
        }
        float m = q[0];
        #pragma unroll
        for (int j = 1; j < NS; ++j) m = fmaxf(m, q[j]);
        float rm = __builtin_amdgcn_rcpf(m);
        #pragma unroll
        for (int j = 0; j < NS; ++j) p[j] = q[j] * rm;
        s += __logf(m);
    }

    float* out = logM + ((long)b * CHUNKS + c) * 49;
    #pragma unroll
    for (int j = 0; j < NS; ++j) {
        float v = p[j];
        out[j * 7 + col] = (v > 0.f) ? (__logf(v) + s) : NEGINF;
    }
}

__global__ __launch_bounds__(256) void crf_combine_kernel(
    const float* __restrict__ feats,
    const float* __restrict__ trans,
    const int*   __restrict__ lengths,
    const float* __restrict__ logM,
    const float* __restrict__ goldp,
    float* __restrict__ perb,
    int B, int T, int L)
{
    int gtid = blockIdx.x * blockDim.x + threadIdx.x;
    int lane = gtid & 7;
    int b    = gtid >> 3;
    if (b >= B) return;
    int len = lengths[b];

    // alpha after t=0: injection from START
    float alpha = (lane < NS) ? (trans[lane * 9 + START_TAG] + feats[(long)b * T * KDIM + lane])
                              : NEGINF;
    int row = (lane < NS) ? lane : 0;
    const float* Mb = logM + (long)b * CHUNKS * 49;

    for (int c = 0; c < CHUNKS; ++c) {
        int tstart = max(c * L, 1);
        if (tstart >= len) break;            // uniform across the 8-lane group
        float a[NS];
        #pragma unroll
        for (int i = 0; i < NS; ++i) a[i] = __shfl(alpha, i, 8);
        const float* Mr = Mb + c * 49 + row * 7;
        float tm = NEGINF;
        float tv[NS];
        #pragma unroll
        for (int i = 0; i < NS; ++i) { tv[i] = Mr[i] + a[i]; tm = fmaxf(tm, tv[i]); }
        float sum = 0.f;
        #pragma unroll
        for (int i = 0; i < NS; ++i) sum += __expf(tv[i] - tm);
        float na = tm + __logf(sum);
        alpha = (lane < NS) ? na : NEGINF;
    }

    // fwd = logsumexp_j(alpha[j] + trans[STOP,j]) across lanes 0..6
    float term = (lane < NS) ? (alpha + trans[STOP_TAG * 9 + lane]) : NEGINF;
    float mm = term;
    #pragma unroll
    for (int off = 4; off > 0; off >>= 1) mm = fmaxf(mm, __shfl_xor(mm, off, 8));
    float e = __expf(term - mm);
    #pragma unroll
    for (int off = 4; off > 0; off >>= 1) e += __shfl_xor(e, off, 8);
    float fwd = mm + __logf(e);

    if (lane == 7) {
        float g = 0.f;
        for (int c = 0; c < CHUNKS; ++c) {
            if (c * L >= len) break;
            g += goldp[b * CHUNKS + c];
        }
        perb[b] = fwd - g;
    }
}

__global__ __launch_bounds__(256) void crf_reduce_kernel(
    const float* __restrict__ perb, float* __restrict__ out, int B)
{
    __shared__ float sdata[256];
    float s = 0.f;
    for (int i = threadIdx.x; i < B; i += 256) s += perb[i];
    sdata[threadIdx.x] = s;
    __syncthreads();
    for (int stride = 128; stride > 0; stride >>= 1) {
        if (threadIdx.x < stride) sdata[threadIdx.x] += sdata[threadIdx.x + stride];
        __syncthreads();
    }
    if (threadIdx.x == 0) out[0] = sdata[0] / (float)B;
}

extern "C" void kernel_launch(void* const* d_in, const int* in_sizes, int n_in,
                              void* d_out, int out_size, void* d_ws, size_t ws_size,
                              hipStream_t stream) {
    const float* feats   = (const float*)d_in[0];
    const float* trans   = (const float*)d_in[1];
    const int*   tags    = (const int*)d_in[2];
    const int*   lengths = (const int*)d_in[3];

    int B = in_sizes[3];
    int T = in_sizes[2] / B;
    int L = (T + CHUNKS - 1) / CHUNKS;   // 64 for T=2048

    float* logM  = (float*)d_ws;                          // B*CHUNKS*49
    float* goldp = logM + (size_t)B * CHUNKS * 49;        // B*CHUNKS
    float* perb  = goldp + (size_t)B * CHUNKS;            // B

    int threadsA = B * CHUNKS * 8;
    crf_chunk_kernel<<<threadsA / 256, 256, 0, stream>>>(
        feats, trans, tags, lengths, logM, goldp, B, T, L);
    crf_combine_kernel<<<(B * 8 + 255) / 256, 256, 0, stream>>>(
        feats, trans, lengths, logM, goldp, perb, B, T, L);
    crf_reduce_kernel<<<1, 256, 0, stream>>>(perb, (float*)d_out, B);
}

// Round 2
// 167.634 us; speedup vs baseline: 1.2058x; 1.2058x over previous
//
#include <hip/hip_runtime.h>

// Fused CRF NLL: B=1024, T=2048, K=9 (START=7, STOP=8).
// One block per sentence (256 thr = 32 chunk-groups x 8 lanes).
// Phase 1: gold score, data-parallel over all threads (8 steps each).
// Phase 2: per-chunk 7x7 linear-space transfer matrix, 1 lane per column,
//          E in SGPRs (readfirstlane), float4 feat loads, renorm every 4.
// Phase 3: threads 0..7 fold 32 log-matrices from LDS, STOP readout,
//          atomicAdd((fwd-gold)/B).

#define START_TAG 7
#define STOP_TAG  8
#define KDIM      9
#define NS        7
#define CHUNKS    32
#define NEGINF    (-1e30f)

__device__ __forceinline__ float rfl(float x) {
    return __int_as_float(__builtin_amdgcn_readfirstlane(__float_as_int(x)));
}

__global__ __launch_bounds__(256) void crf_fused_kernel(
    const float* __restrict__ feats,
    const float* __restrict__ trans,
    const int*   __restrict__ tags,
    const int*   __restrict__ lengths,
    float* __restrict__ out,
    int B, int T, int L)
{
    __shared__ float s_trans[81];
    __shared__ float s_E[49];
    __shared__ float s_M[CHUNKS * 64];   // [c][j*8 + i], padded rows of 8
    __shared__ float s_gold[4];

    const int tid = threadIdx.x;
    const int b   = blockIdx.x;

    if (tid < 81) s_trans[tid] = trans[tid];
    if (tid >= 128 && tid < 128 + 49) {
        int k = tid - 128;
        s_E[k] = __expf(trans[(k / 7) * 9 + (k % 7)]);
    }
    __syncthreads();

    const int    len   = lengths[b];
    const int*   tg    = tags  + (size_t)b * T;
    const float* fbase = feats + (size_t)b * T * KDIM;

    // ---------------- phase 1: gold score ----------------
    {
        int per = T >> 8;                 // 8 for T=2048
        int t0  = tid * per;
        float g = 0.f;
        if (t0 < len) {
            int te   = min(t0 + per, len);
            int prev = (t0 == 0) ? START_TAG : tg[t0 - 1];
            for (int t = t0; t < te; ++t) {
                int cur = tg[t];
                g += s_trans[cur * 9 + prev] + fbase[(size_t)t * KDIM + cur];
                prev = cur;
            }
            if (len - 1 < t0 + per) g += s_trans[STOP_TAG * 9 + tg[len - 1]];
        }
        #pragma unroll
        for (int off = 32; off > 0; off >>= 1) g += __shfl_xor(g, off, 64);
        if ((tid & 63) == 0) s_gold[tid >> 6] = g;
    }

    // ---------------- phase 2: chunk matrices ----------------
    {
        const int lane8 = tid & 7;
        const int c     = tid >> 3;
        const int t0    = c * L;
        const int tstart = max(t0, 1);
        const int tend   = min(t0 + L, len);

        if (lane8 < NS) {
            const int col = lane8;
            float* Mw = s_M + c * 64;
            if (tstart < tend) {
                // uniform E -> SGPRs
                float E[49];
                #pragma unroll
                for (int k = 0; k < 49; ++k) E[k] = rfl(s_E[k]);

                float p[NS];
                #pragma unroll
                for (int j = 0; j < NS; ++j) p[j] = (j == col) ? 1.f : 0.f;
                float s = 0.f;

                const float* fp = fbase + (size_t)tstart * KDIM;
                int steps = tend - tstart;

                #define CRF_STEP() do {                                         \
                    float4 fA = *(const float4*)fp;                             \
                    float4 fB = *(const float4*)(fp + 4);                       \
                    fp += KDIM;                                                 \
                    float f[NS] = {fA.x, fA.y, fA.z, fA.w, fB.x, fB.y, fB.z};   \
                    float q[NS];                                                \
                    _Pragma("unroll")                                           \
                    for (int j = 0; j < NS; ++j) {                              \
                        float acc = E[j * 7] * p[0];                            \
                        _Pragma("unroll")                                       \
                        for (int i = 1; i < NS; ++i)                            \
                            acc = fmaf(E[j * 7 + i], p[i], acc);                \
                        q[j] = acc * __expf(f[j]);                              \
                    }                                                           \
                    _Pragma("unroll")                                           \
                    for (int j = 0; j < NS; ++j) p[j] = q[j];                   \
                } while (0)

                #define CRF_RENORM() do {                                       \
                    float m = p[0];                                             \
                    _Pragma("unroll")                                           \
                    for (int j = 1; j < NS; ++j) m = fmaxf(m, p[j]);            \
                    float rm = __builtin_amdgcn_rcpf(m);                        \
                    _Pragma("unroll")                                           \
                    for (int j = 0; j < NS; ++j) p[j] *= rm;                    \
                    s += __logf(m);                                             \
                } while (0)

                while (steps >= 4) {
                    CRF_STEP(); CRF_STEP(); CRF_STEP(); CRF_STEP();
                    CRF_RENORM();
                    steps -= 4;
                }
                if (steps > 0) {
                    while (steps-- > 0) { CRF_STEP(); }
                    CRF_RENORM();
                }

                #pragma unroll
                for (int j = 0; j < NS; ++j)
                    Mw[j * 8 + col] = __logf(p[j]) + s;
            } else {
                // inactive chunk: identity (log space)
                #pragma unroll
                for (int j = 0; j < NS; ++j)
                    Mw[j * 8 + col] = (j == col) ? 0.f : NEGINF;
            }
        }
    }
    __syncthreads();

    // ---------------- phase 3: fold + output ----------------
    if (tid < 8) {
        const int lane = tid;
        const bool isrow = (lane < NS);
        const int row = isrow ? lane : 0;

        float a, S;
        {
            float a0 = isrow ? (s_trans[lane * 9 + START_TAG] + fbase[lane]) : NEGINF;
            float m = a0;
            #pragma unroll
            for (int off = 4; off > 0; off >>= 1) m = fmaxf(m, __shfl_xor(m, off, 8));
            a = a0 - m;
            S = m;
        }

        const int nc = (len + L - 1) / L;
        for (int c = 0; c < nc; ++c) {
            const float* Mr = s_M + c * 64 + row * 8;
            float tv[NS];
            float tm = NEGINF;
            #pragma unroll
            for (int i = 0; i < NS; ++i) {
                float ai = __shfl(a, i, 8);
                tv[i] = Mr[i] + ai;
                tm = fmaxf(tm, tv[i]);
            }
            float sum = 0.f;
            #pragma unroll
            for (int i = 0; i < NS; ++i) sum += __expf(tv[i] - tm);
            float na = tm + __logf(sum);
            float m2 = na;
            #pragma unroll
            for (int off = 4; off > 0; off >>= 1) m2 = fmaxf(m2, __shfl_xor(m2, off, 8));
            a = na - m2;
            S += m2;
        }

        float term = isrow ? (a + s_trans[STOP_TAG * 9 + lane]) : NEGINF;
        float tm2 = term;
        #pragma unroll
        for (int off = 4; off > 0; off >>= 1) tm2 = fmaxf(tm2, __shfl_xor(tm2, off, 8));
        float e = isrow ? __expf(term - tm2) : 0.f;
        #pragma unroll
        for (int off = 4; off > 0; off >>= 1) e += __shfl_xor(e, off, 8);

        if (lane == 0) {
            float fwd = S + tm2 + __logf(e);
            float g = s_gold[0] + s_gold[1] + s_gold[2] + s_gold[3];
            atomicAdd(out, (fwd - g) * (1.0f / (float)B));
        }
    }
}

__global__ void init_out_kernel(float* out) {
    if (threadIdx.x == 0) out[0] = 0.f;
}

extern "C" void kernel_launch(void* const* d_in, const int* in_sizes, int n_in,
                              void* d_out, int out_size, void* d_ws, size_t ws_size,
                              hipStream_t stream) {
    const float* feats   = (const float*)d_in[0];
    const float* trans   = (const float*)d_in[1];
    const int*   tags    = (const int*)d_in[2];
    const int*   lengths = (const int*)d_in[3];

    int B = in_sizes[3];
    int T = in_sizes[2] / B;
    int L = (T + CHUNKS - 1) / CHUNKS;   // 64 for T=2048

    init_out_kernel<<<1, 64, 0, stream>>>((float*)d_out);
    crf_fused_kernel<<<B, 256, 0, stream>>>(
        feats, trans, tags, lengths, (float*)d_out, B, T, L);
}

// Round 3
// 156.960 us; speedup vs baseline: 1.2878x; 1.0680x over previous
//
#include <hip/hip_runtime.h>

// Fused CRF NLL: B=1024, T=2048, K=9 (START=7, STOP=8).
// One block per sentence (256 thr = 32 chunk-groups x 8 lanes).
// Phase 1: gold score, data-parallel, unrolled-8 loads.
// Phase 2: per-chunk 7x7 linear-space transfer matrix, 1 lane per column.
//   - E in SGPRs (readfirstlane)
//   - lane l loads ONLY f[t][l] (1 dword/step), exp once, shares via ds_bpermute
//   - 4-step software pipeline (explicit register prefetch, clamped tails)
//   - renorm every 4 steps (growth bounded ~1e17, fp32-safe)
// Phase 3: threads 0..7 fold 32 log-matrices from LDS with next-row prefetch,
//   STOP readout, atomicAdd((fwd-gold)/B).

#define START_TAG 7
#define STOP_TAG  8
#define KDIM      9
#define NS        7
#define CHUNKS    32
#define NEGINF    (-1e30f)

__device__ __forceinline__ float rfl(float x) {
    return __int_as_float(__builtin_amdgcn_readfirstlane(__float_as_int(x)));
}

__global__ __launch_bounds__(256) void crf_fused_kernel(
    const float* __restrict__ feats,
    const float* __restrict__ trans,
    const int*   __restrict__ tags,
    const int*   __restrict__ lengths,
    float* __restrict__ out,
    int B, int T, int L)
{
    __shared__ float s_trans[81];
    __shared__ float s_E[49];
    __shared__ float s_M[CHUNKS * 64];   // [c][j*8 + i] rows padded to 8
    __shared__ float s_gold[4];

    const int tid = threadIdx.x;
    const int b   = blockIdx.x;

    if (tid < 81) s_trans[tid] = trans[tid];
    if (tid >= 128 && tid < 177) {
        int k = tid - 128;
        s_E[k] = __expf(trans[(k / 7) * 9 + (k % 7)]);
    }
    __syncthreads();

    const int    len   = lengths[b];
    const int*   tg    = tags  + (size_t)b * T;
    const float* fbase = feats + (size_t)b * T * KDIM;

    // ---------------- phase 1: gold score ----------------
    {
        int per = (T >> 8) > 0 ? (T >> 8) : 1;
        int t0  = tid * per;
        float g = 0.f;
        if (t0 < len) {
            int te   = min(t0 + per, len);
            int prev = (t0 == 0) ? START_TAG : tg[t0 - 1];
            if (per == 8) {
                #pragma unroll
                for (int k = 0; k < 8; ++k) {
                    int t   = t0 + k;
                    int tc  = min(t, te - 1);
                    int cur = tg[tc];
                    float v = s_trans[cur * 9 + prev] + fbase[(size_t)tc * KDIM + cur];
                    g += (t < te) ? v : 0.f;
                    prev = cur;
                }
            } else {
                for (int k = 0; k < per; ++k) {
                    int t   = t0 + k;
                    int tc  = min(t, te - 1);
                    int cur = tg[tc];
                    float v = s_trans[cur * 9 + prev] + fbase[(size_t)tc * KDIM + cur];
                    g += (t < te) ? v : 0.f;
                    prev = cur;
                }
            }
            if (len - 1 >= t0 && len - 1 < t0 + per)
                g += s_trans[STOP_TAG * 9 + tg[len - 1]];
        }
        #pragma unroll
        for (int off = 32; off > 0; off >>= 1) g += __shfl_xor(g, off, 64);
        if ((tid & 63) == 0) s_gold[tid >> 6] = g;
    }

    // ---------------- phase 2: chunk matrices ----------------
    {
        const int lane8  = tid & 7;
        const int c      = tid >> 3;
        const int t0     = c * L;
        const int tstart = max(t0, 1);
        const int tend   = min(t0 + L, len);

        if (lane8 < NS) {
            float* Mw = s_M + c * 64;
            if (tstart < tend) {
                float E[49];
                #pragma unroll
                for (int k = 0; k < 49; ++k) E[k] = rfl(s_E[k]);

                // precomputed bpermute byte addresses for lanes (group base | j)
                int baddr[NS];
                #pragma unroll
                for (int j = 0; j < NS; ++j) baddr[j] = (((tid & 56) | j) << 2);

                float p[NS];
                #pragma unroll
                for (int j = 0; j < NS; ++j) p[j] = (j == lane8) ? 1.f : 0.f;
                float s = 0.f;
                int rem = tend - tstart;

                const float* fp = fbase + (size_t)tstart * KDIM + lane8;

                #define CRF_STEP(XF) do {                                       \
                    float q[NS];                                                \
                    _Pragma("unroll")                                           \
                    for (int j = 0; j < NS; ++j) {                              \
                        float acc = E[j * 7] * p[0];                            \
                        _Pragma("unroll")                                       \
                        for (int i = 1; i < NS; ++i)                            \
                            acc = fmaf(E[j * 7 + i], p[i], acc);                \
                        q[j] = acc;                                             \
                    }                                                           \
                    float myef = __expf(XF);                                    \
                    _Pragma("unroll")                                           \
                    for (int j = 0; j < NS; ++j) {                              \
                        float efj = __int_as_float(                             \
                            __builtin_amdgcn_ds_bpermute(                       \
                                baddr[j], __float_as_int(myef)));               \
                        p[j] = q[j] * efj;                                      \
                    }                                                           \
                } while (0)

                #define CRF_RENORM() do {                                       \
                    float m = p[0];                                             \
                    _Pragma("unroll")                                           \
                    for (int j = 1; j < NS; ++j) m = fmaxf(m, p[j]);            \
                    float rm = __builtin_amdgcn_rcpf(m);                        \
                    _Pragma("unroll")                                           \
                    for (int j = 0; j < NS; ++j) p[j] *= rm;                    \
                    s += __logf(m);                                             \
                } while (0)

                // initial preload (clamped so short chunks never read OOB)
                int o1 = KDIM * min(1, rem - 1);
                int o2 = KDIM * min(2, rem - 1);
                int o3 = KDIM * min(3, rem - 1);
                float x0 = fp[0], x1 = fp[o1], x2 = fp[o2], x3 = fp[o3];
                fp += 4 * KDIM;

                while (rem >= 8) {
                    float y0 = fp[0], y1 = fp[KDIM], y2 = fp[2 * KDIM], y3 = fp[3 * KDIM];
                    fp += 4 * KDIM;
                    CRF_STEP(x0); CRF_STEP(x1); CRF_STEP(x2); CRF_STEP(x3);
                    CRF_RENORM();
                    x0 = y0; x1 = y1; x2 = y2; x3 = y3;
                    rem -= 4;
                }
                if (rem > 4) {
                    int e1 = KDIM * min(1, rem - 5);
                    int e2 = KDIM * min(2, rem - 5);
                    float y0 = fp[0], y1 = fp[e1], y2 = fp[e2];
                    CRF_STEP(x0); CRF_STEP(x1); CRF_STEP(x2); CRF_STEP(x3);
                    CRF_RENORM();
                    x0 = y0; x1 = y1; x2 = y2;
                    rem -= 4;
                }
                // rem in [1,4]
                CRF_STEP(x0);
                if (rem > 1) CRF_STEP(x1);
                if (rem > 2) CRF_STEP(x2);
                if (rem > 3) CRF_STEP(x3);

                #pragma unroll
                for (int j = 0; j < NS; ++j)
                    Mw[j * 8 + lane8] = __logf(p[j]) + s;
                #undef CRF_STEP
                #undef CRF_RENORM
            } else {
                #pragma unroll
                for (int j = 0; j < NS; ++j)
                    Mw[j * 8 + lane8] = (j == lane8) ? 0.f : NEGINF;
            }
        }
    }
    __syncthreads();

    // ---------------- phase 3: fold + output ----------------
    if (tid < 8) {
        const int  lane  = tid;
        const bool isrow = (lane < NS);
        const int  row   = isrow ? lane : 0;

        float a, S;
        {
            float a0 = isrow ? (s_trans[lane * 9 + START_TAG] + fbase[lane]) : NEGINF;
            float m = a0;
            #pragma unroll
            for (int off = 4; off > 0; off >>= 1) m = fmaxf(m, __shfl_xor(m, off, 8));
            a = a0 - m;
            S = m;
        }

        const int nc = min(CHUNKS, (len + L - 1) / L);
        const float* Mr0 = s_M + row * 8;
        float4 mA = *(const float4*)(Mr0);
        float4 mB = *(const float4*)(Mr0 + 4);
        for (int c = 0; c < nc; ++c) {
            int cn = min(c + 1, CHUNKS - 1);
            float4 nA = *(const float4*)(Mr0 + cn * 64);
            float4 nB = *(const float4*)(Mr0 + cn * 64 + 4);
            float tv[NS] = { mA.x, mA.y, mA.z, mA.w, mB.x, mB.y, mB.z };
            float tm = NEGINF;
            #pragma unroll
            for (int i = 0; i < NS; ++i) {
                tv[i] += __shfl(a, i, 8);
                tm = fmaxf(tm, tv[i]);
            }
            float sum = 0.f;
            #pragma unroll
            for (int i = 0; i < NS; ++i) sum += __expf(tv[i] - tm);
            float na = isrow ? (tm + __logf(sum)) : NEGINF;
            float m2 = na;
            #pragma unroll
            for (int off = 4; off > 0; off >>= 1) m2 = fmaxf(m2, __shfl_xor(m2, off, 8));
            a = na - m2;
            S += m2;
            mA = nA; mB = nB;
        }

        float term = isrow ? (a + s_trans[STOP_TAG * 9 + lane]) : NEGINF;
        float tm2 = term;
        #pragma unroll
        for (int off = 4; off > 0; off >>= 1) tm2 = fmaxf(tm2, __shfl_xor(tm2, off, 8));
        float e = isrow ? __expf(term - tm2) : 0.f;
        #pragma unroll
        for (int off = 4; off > 0; off >>= 1) e += __shfl_xor(e, off, 8);

        if (lane == 0) {
            float fwd = S + tm2 + __logf(e);
            float g = s_gold[0] + s_gold[1] + s_gold[2] + s_gold[3];
            atomicAdd(out, (fwd - g) * (1.0f / (float)B));
        }
    }
}

__global__ void init_out_kernel(float* out) {
    if (threadIdx.x == 0) out[0] = 0.f;
}

extern "C" void kernel_launch(void* const* d_in, const int* in_sizes, int n_in,
                              void* d_out, int out_size, void* d_ws, size_t ws_size,
                              hipStream_t stream) {
    const float* feats   = (const float*)d_in[0];
    const float* trans   = (const float*)d_in[1];
    const int*   tags    = (const int*)d_in[2];
    const int*   lengths = (const int*)d_in[3];

    int B = in_sizes[3];
    int T = in_sizes[2] / B;
    int L = (T + CHUNKS - 1) / CHUNKS;   // 64 for T=2048

    init_out_kernel<<<1, 64, 0, stream>>>((float*)d_out);
    crf_fused_kernel<<<B, 256, 0, stream>>>(
        feats, trans, tags, lengths, (float*)d_out, B, T, L);
}